// Round 11
// baseline (89.009 us; speedup 1.0000x reference)
//
#include <hip/hip_runtime.h>

// SoftHistogram: x[B=64, N=1000, F=256] fp32 -> out[B, F*K=2048] fp32
// out[b, f*8+k] = mean_n relu(1 - 16*|x[b,n,f] - (k+0.5)/8|)
//
// R11 = R9 structure + ds_add_f32 accumulation (via unsafeAtomicAdd on LDS):
// the hot-loop histogram update becomes one fire-and-forget DS instr per
// element (was read->stall->add->write = 2 DS + lgkmcnt chain). 4 DS/float4
// instead of 8, no read latency on the critical path, add off the VALU.
// Deterministic: slot = ki*256 + i*64 + l is lane-unique (l), histograms are
// wave-private -> per-address order = program order. Bank = l%32 (2/bank,
// free). Unconditional add (max(y,0)=0 is exact) -- no exec-mask churn.
// Single dispatch, 512 blocks x 512 thr, 64 KB LDS (2 blocks/CU), no ws.

constexpr int N = 1000, F = 256, K = 8;
constexpr int FG = 32;             // features per block
constexpr int WPB = 8;             // waves per block
constexpr int NS = 64;             // n-subgroup stride

__global__ __launch_bounds__(512) void softhist_mono(const float* __restrict__ x,
                                                     float* __restrict__ out) {
    __shared__ float hist[WPB * K * F];   // 8 waves x [k][256 slots] = 64 KB

    const int bid = blockIdx.x;
    const int b  = bid >> 3;
    const int f0 = (bid & 7) * FG;
    const int t  = threadIdx.x;
    const int w  = t >> 6;             // wave 0..7
    const int l  = t & 63;             // lane

    float* wh = &hist[w * (K * F)];    // this wave's private 2048-float hist

    // wave-private zero (own 8 KB only; LDS in-order per wave -> no barrier)
#pragma unroll
    for (int z = 0; z < 8; ++z)
        reinterpret_cast<float4*>(wh)[z * 64 + l] = float4{0.f, 0.f, 0.f, 0.f};

    const int nsub = t >> 3;
    const float* base = x + (size_t)b * N * F + f0 + (l & 7) * 4;

    auto proc = [&](const float4 v) {
        const float xs[4] = {v.x, v.y, v.z, v.w};
#pragma unroll
        for (int i = 0; i < 4; ++i) {
            const float h  = fmaf(xs[i], 8.0f, -0.5f);            // u = 8x-0.5
            const float kf = __builtin_rintf(h);                   // v_rndne
            const float kc = __builtin_amdgcn_fmed3f(kf, 0.0f, 7.0f);
            const float y  = fmaxf(fmaf(-2.0f, fabsf(h - kc), 1.0f), 0.0f);
            // ds_add_f32: fire-and-forget, lane-unique addr, bank = l%32
            unsafeAtomicAdd(&wh[(int)kc * F + (i << 6) + l], y);
        }
    };

    int n = nsub;
    for (; n + NS < N; n += 2 * NS) {
        const float4 v0 = *reinterpret_cast<const float4*>(base + (size_t)n * F);
        const float4 v1 = *reinterpret_cast<const float4*>(base + (size_t)(n + NS) * F);
        proc(v0);
        proc(v1);
    }
    if (n < N)
        proc(*reinterpret_cast<const float4*>(base + (size_t)n * F));

    __syncthreads();

    // Epilogue (R9, proven): output (f in [0,32), k in [0,8)).
    // term slot = k*256 + (f&3)*64 + g*8 + (f>>2); g staggered -> 32 banks.
    if (t < FG * K) {   // 256 threads
        const int f = t & 31;
        const int k = t >> 5;
        const int slot_base = k * F + ((f & 3) << 6) + (f >> 2);
        float s = 0.0f;
#pragma unroll
        for (int w2 = 0; w2 < WPB; ++w2)
#pragma unroll
            for (int g = 0; g < 8; ++g) {
                const int gp = (g + (f & 7)) & 7;
                s += hist[w2 * (K * F) + slot_base + gp * 8];
            }
        out[(size_t)b * (F * K) + (f0 + f) * K + k] = s * (1.0f / (float)N);
    }
}

extern "C" void kernel_launch(void* const* d_in, const int* in_sizes, int n_in,
                              void* d_out, int out_size, void* d_ws, size_t ws_size,
                              hipStream_t stream) {
    const float* x = (const float*)d_in[0];
    float* out = (float*)d_out;
    // 64 b x 8 f-slices -> 512 blocks of 512 threads (2 blocks/CU)
    softhist_mono<<<dim3(512), dim3(512), 0, stream>>>(x, out);
}

// Round 12
// 16.588 us; speedup vs baseline: 5.3659x; 5.3659x over previous
//
#include <hip/hip_runtime.h>

// SoftHistogram: x[B=64, N=1000, F=256] fp32 -> out[B, F*K=2048] fp32
// out[b, f*8+k] = mean_n relu(1 - 16*|x[b,n,f] - (k+0.5)/8|)
//
// R12 = R9 (best, 17.4us) + XCD page-locality remap. R9's decomposition
// said the 8 column-blocks of each batch row b interleave 128-B reads of
// the same 1-KB DRAM rows from 8 different XCDs (dispatch%8 round-robin)
// -> DRAM page-hit rate collapses. Remap the bid decomposition so all 8
// blocks of one b share an XCD: with d = blockIdx.x, choose b = d&63,
// c = d>>6  =>  d%8 == b%8 for every c (same-b blocks co-resident on one
// XCD, their same-page requests adjacent in that XCD's request stream).
// Everything else is R9 verbatim: nearest-bin (u=8x-0.5, k*=clamp(round u),
// y=relu(1-2|u-k*|)), wave-private LDS hist, lane-unique slot
// ki*256+i*64+l (bank=l%32, conflict-free), g-staggered epilogue.
// Single dispatch, 512 blocks x 512 thr, 64 KB LDS (2 blocks/CU), no ws.

constexpr int N = 1000, F = 256, K = 8;
constexpr int FG = 32;             // features per block
constexpr int WPB = 8;             // waves per block
constexpr int NS = 64;             // n-subgroup stride

__global__ __launch_bounds__(512) void softhist_mono(const float* __restrict__ x,
                                                     float* __restrict__ out) {
    __shared__ float hist[WPB * K * F];   // 8 waves x [k][256 slots] = 64 KB

    const int bid = blockIdx.x;
    const int b  = bid & 63;           // XCD remap: dispatch%8 == b%8
    const int f0 = (bid >> 6) * FG;    // column slice c = bid>>6
    const int t  = threadIdx.x;
    const int w  = t >> 6;             // wave 0..7
    const int l  = t & 63;             // lane

    float* wh = &hist[w * (K * F)];    // this wave's private 2048-float hist

    // wave-private zero (own 8 KB only; LDS in-order per wave -> no barrier)
#pragma unroll
    for (int z = 0; z < 8; ++z)
        reinterpret_cast<float4*>(wh)[z * 64 + l] = float4{0.f, 0.f, 0.f, 0.f};

    const int nsub = t >> 3;
    const float* base = x + (size_t)b * N * F + f0 + (l & 7) * 4;

    auto proc = [&](const float4 v) {
        const float xs[4] = {v.x, v.y, v.z, v.w};
#pragma unroll
        for (int i = 0; i < 4; ++i) {
            const float h  = fmaf(xs[i], 8.0f, -0.5f);            // u = 8x-0.5
            const float kf = __builtin_rintf(h);                   // v_rndne
            const float kc = __builtin_amdgcn_fmed3f(kf, 0.0f, 7.0f);
            const float y  = fmaf(-2.0f, fabsf(h - kc), 1.0f);     // 1-2|u-k*|
            if (y > 0.0f) {                                        // ~34% lanes
                const int ki = (int)kc;
                wh[ki * F + (i << 6) + l] += y;   // bank = l%32: conflict-free
            }
        }
    };

    int n = nsub;
    for (; n + NS < N; n += 2 * NS) {
        const float4 v0 = *reinterpret_cast<const float4*>(base + (size_t)n * F);
        const float4 v1 = *reinterpret_cast<const float4*>(base + (size_t)(n + NS) * F);
        proc(v0);
        proc(v1);
    }
    if (n < N)
        proc(*reinterpret_cast<const float4*>(base + (size_t)n * F));

    __syncthreads();

    // Epilogue (R9, proven): output (f in [0,32), k in [0,8)).
    // term slot = k*256 + (f&3)*64 + g*8 + (f>>2); g staggered -> 32 banks.
    if (t < FG * K) {   // 256 threads
        const int f = t & 31;
        const int k = t >> 5;
        const int slot_base = k * F + ((f & 3) << 6) + (f >> 2);
        float s = 0.0f;
#pragma unroll
        for (int w2 = 0; w2 < WPB; ++w2)
#pragma unroll
            for (int g = 0; g < 8; ++g) {
                const int gp = (g + (f & 7)) & 7;
                s += hist[w2 * (K * F) + slot_base + gp * 8];
            }
        out[(size_t)b * (F * K) + (f0 + f) * K + k] = s * (1.0f / (float)N);
    }
}

extern "C" void kernel_launch(void* const* d_in, const int* in_sizes, int n_in,
                              void* d_out, int out_size, void* d_ws, size_t ws_size,
                              hipStream_t stream) {
    const float* x = (const float*)d_in[0];
    float* out = (float*)d_out;
    // 64 b x 8 f-slices -> 512 blocks of 512 threads (2 blocks/CU)
    softhist_mono<<<dim3(512), dim3(512), 0, stream>>>(x, out);
}